// Round 6
// baseline (174.952 us; speedup 1.0000x reference)
//
#include <hip/hip_runtime.h>

#define L_DIM 4096
#define B_DIM 4
#define KNN 48
#define CAP 1536            // survivor cap; data needs ~50-60
#define INVALID_X2 1.0e30f  // encodes mask=0: d^2 ~ 1e30, never selectable
#define SLACK 8u            // ulp slack on d^2 threshold covering sqrt collisions

// ---------------------------------------------------------------------------
// prep: c4 = (x, y, z, valid ? x2 : 1e30); per-batch n_valid via one ballot +
// lane0 atomic per wave (single-address, coalesced-friendly — G12-safe).
// x2 contracted-FMA chain (matches XLA:CPU fused codegen); dot(i,i) == x2(i)
// bit-exact => D[i,i] == 0 exactly.
// ---------------------------------------------------------------------------
__global__ __launch_bounds__(256) void prep_kernel(const float* __restrict__ X,
                                                   const float* __restrict__ mask,
                                                   float4* __restrict__ c4,
                                                   int* __restrict__ nvalid) {
#pragma clang fp contract(off)
    int i = blockIdx.x * 256 + threadIdx.x;              // i in [0, B*L)
    const float4* X4 = (const float4*)X;                 // residue = 3 aligned float4
    float4 a = X4[3 * i];                                // ... f3(=CA x)
    float4 bb = X4[3 * i + 1];                           // f4(=CA y) f5(=CA z) ...
    float x = a.w, y = bb.x, z = bb.y;
    float x2 = __builtin_fmaf(z, z, __builtin_fmaf(y, y, x * x));
    float m = mask[i];
    c4[i] = make_float4(x, y, z, (m > 0.0f) ? x2 : INVALID_X2);
    unsigned long long bal = __ballot(m > 0.0f);
    if ((threadIdx.x & 63) == 0)
        atomicAdd(&nvalid[i >> 12], (int)__popcll(bal));  // block spans one batch
}

// ---------------------------------------------------------------------------
// main: one block per (b,i) row, 256 threads, 16 candidates/thread.
//  A: d^2 -> u32 bits in registers (no sqrt in hot loop; bit-monotone >= +0).
//  B: wave bitonic sort of 64 per-thread minima; T2 = min over waves of the
//     48th-smallest (certified >= q48 = 48th-smallest d^2: at most 47 values
//     are < q48, so at most 47 minima in ANY wave are < q48).
//  C: compact survivors (d2b <= T2+SLACK) into LDS; SLACK covers d^2 > T2
//     with sqrt(d^2) == sqrt(T2) (preimage ~2 ulps wide).
//  D1: survivors get exact keys (sqrtf_bits<<32 | j) — correctly-rounded sqrt
//      only ~56x per block.
//  D2: rank-count (exact (d, idx) order = lax.top_k tie-break), scatter top-48.
// ---------------------------------------------------------------------------
__global__ __launch_bounds__(256) void knn_kernel(const float4* __restrict__ c4,
                                                  const float* __restrict__ mask,
                                                  const int* __restrict__ nvalid,
                                                  float* __restrict__ dn,
                                                  float* __restrict__ ei) {
    __shared__ unsigned long long surv[CAP];
    __shared__ unsigned tminw[4];
    __shared__ int cnt;

    const int row = blockIdx.x;                // b*L + i
    const int b = row >> 12;
    const int i = row & (L_DIM - 1);
    const int t = threadIdx.x;
    const int lane = t & 63;

    float* dnrow = dn + (size_t)row * KNN;
    float* eirow = ei + (size_t)row * KNN;

    // degenerate batch or invalid query row -> self-fill (block-uniform)
    if (nvalid[b] <= KNN || !(mask[row] > 0.0f)) {
        if (t < KNN) { dnrow[t] = 0.0f; eirow[t] = (float)i; }
        return;
    }

    // ---- A: d^2 bit patterns + running per-thread min ----
    unsigned db2[16];
    unsigned sv = 0xFFFFFFFFu;
    {
#pragma clang fp contract(off)
        const float4 q = c4[(size_t)b * L_DIM + i];      // q.w = x2_i (row valid)
        const float4* cb = c4 + (size_t)b * L_DIM;
#pragma unroll
        for (int it = 0; it < 16; ++it) {
            int j = it * 256 + t;
            float4 pj = cb[j];
            float dot = __builtin_fmaf(pj.z, q.z,
                        __builtin_fmaf(pj.y, q.y, pj.x * q.x));
            // fma(-2,dot,t1) == (t1 - 2*dot) bit-exactly: 2*dot exact, 1 rounding
            float d2 = fmaxf(__builtin_fmaf(-2.0f, dot, q.w + pj.w), 0.0f);
            db2[it] = __float_as_uint(d2);
            sv = min(sv, db2[it]);
        }
    }
    if (t == 0) cnt = 0;

    // ---- B: wave bitonic sort of 64 minima; T2 certified >= q48 ----
#pragma unroll
    for (int k = 2; k <= 64; k <<= 1) {
#pragma unroll
        for (int j = k >> 1; j > 0; j >>= 1) {
            unsigned o = __shfl_xor(sv, j);
            unsigned mn = min(sv, o), mx = max(sv, o);
            bool asc = ((lane & k) == 0);
            bool low = ((lane & j) == 0);
            sv = (asc == low) ? mn : mx;
        }
    }
    unsigned Tw = __shfl(sv, 47);              // wave's 48th-smallest minimum
    if (lane == 0) tminw[t >> 6] = Tw;
    __syncthreads();
    const unsigned Tp = min(min(tminw[0], tminw[1]), min(tminw[2], tminw[3])) + SLACK;

    // ---- C: compact survivors ----
#pragma unroll
    for (int it = 0; it < 16; ++it) {
        if (db2[it] <= Tp) {
            int pos = atomicAdd(&cnt, 1);      // LDS atomic
            if (pos < CAP) {
                unsigned j = (unsigned)(it * 256 + t);
                surv[pos] = ((unsigned long long)db2[it] << 32) | j;
            }
        }
    }
    __syncthreads();

    int S = cnt; if (S > CAP) S = CAP;

    // ---- D1: exact keys — correctly-rounded sqrt for survivors only ----
    for (int c = t; c < S; c += 256) {
        unsigned long long key = surv[c];
        float d = sqrtf(__uint_as_float((unsigned)(key >> 32)));
        surv[c] = ((unsigned long long)__float_as_uint(d) << 32)
                | (key & 0xFFFFFFFFULL);
    }
    __syncthreads();

    // ---- D2: exact rank among survivors, scatter top-48 ----
    for (int c = t; c < S; c += 256) {
        unsigned long long key = surv[c];
        int rank = 0;
        for (int s = 0; s < S; ++s) rank += (surv[s] < key);  // broadcast reads
        if (rank < KNN) {
            dnrow[rank] = __uint_as_float((unsigned)(key >> 32));
            eirow[rank] = (float)(key & 0xFFFFFFFFULL);
        }
    }
}

extern "C" void kernel_launch(void* const* d_in, const int* in_sizes, int n_in,
                              void* d_out, int out_size, void* d_ws, size_t ws_size,
                              hipStream_t stream) {
    const float* X = (const float*)d_in[0];
    const float* mask = (const float*)d_in[1];

    float* out = (float*)d_out;
    float* dn = out;                                   // (B,L,K) D_neighbors
    float* ei = out + (size_t)B_DIM * L_DIM * KNN;     // (B,L,K) E_idx as f32

    char* ws = (char*)d_ws;
    float4* c4 = (float4*)ws;                          // 256 KiB
    int* nv = (int*)(ws + (size_t)B_DIM * L_DIM * 16);

    hipMemsetAsync(nv, 0, B_DIM * sizeof(int), stream);
    prep_kernel<<<(B_DIM * L_DIM) / 256, 256, 0, stream>>>(X, mask, c4, nv);
    knn_kernel<<<B_DIM * L_DIM, 256, 0, stream>>>(c4, mask, nv, dn, ei);
}